// Round 10
// baseline (8311.977 us; speedup 1.0000x reference)
//
#include <hip/hip_runtime.h>

#define NT 512
#define TRAJ 4

constexpr int Lk = 200;
constexpr int NSTEPS = 100;

typedef float f32x2 __attribute__((ext_vector_type(2)));

#if __has_builtin(__builtin_elementwise_fma)
#define FMA2(a, b, c) __builtin_elementwise_fma((a), (b), (c))
#else
static __device__ __forceinline__ f32x2 fma2_(f32x2 a, f32x2 b, f32x2 c) {
    c.x = fmaf(a.x, b.x, c.x); c.y = fmaf(a.y, b.y, c.y); return c;
}
#define FMA2 fma2_
#endif

// Stable softplus, matches jax.nn.softplus in fp32: max(x,0) + log1p(exp(-|x|))
__device__ __forceinline__ float sp_act(float x) {
    return fmaxf(x, 0.0f) + log1pf(expf(-fabsf(x)));
}

// fp32 -> bf16 round-to-nearest-even (low 16 bits of result)
__device__ __forceinline__ unsigned int f2bf(float f) {
    union { float f; unsigned int u; } v; v.f = f;
    unsigned int u = v.u + 0x7FFFu + ((v.u >> 16) & 1u);
    return u >> 16;
}

// d = a.bf16[0]*b.bf16[0] + a.bf16[1]*b.bf16[1] + c
// Prefer the clang builtin (dot9-insts); inline asm only as fallback.
#if defined(__has_builtin) && __has_builtin(__builtin_amdgcn_fdot2_f32_bf16)
typedef __bf16 bf16x2 __attribute__((ext_vector_type(2)));
__device__ __forceinline__ float dot2bf(unsigned int a, unsigned int b, float c) {
    return __builtin_amdgcn_fdot2_f32_bf16(__builtin_bit_cast(bf16x2, a),
                                           __builtin_bit_cast(bf16x2, b), c, false);
}
#else
__device__ __forceinline__ float dot2bf(unsigned int a, unsigned int b, float c) {
    float d;
    asm("v_dot2_f32_bf16 %0, %1, %2, %3" : "=v"(d) : "v"(a), "v"(b), "v"(c));
    return d;
}
#endif

// Pack fW3 [2048][128] f32 -> bf16 k-pairs, R1's PROVEN address pattern (FETCH ~23MB):
// u32 slot idx = kp*2048 + n holds (w[n][2kp], w[n][2kp+1]).
// Main kernel reads uint4 at kp*512 + tid -> pairs for n = 4*tid..4*tid+3, lane-contiguous 16B.
__global__ void fw3_packp(const float* __restrict__ w, unsigned int* __restrict__ p) {
    const int idx = blockIdx.x * 256 + threadIdx.x;   // 0..131071
    const int kp = idx >> 11;       // 0..63
    const int n  = idx & 2047;      // 0..2047
    const float2 v = *(const float2*)(w + n * 128 + 2 * kp);
    p[idx] = f2bf(v.x) | (f2bf(v.y) << 16);
}

// Stage global weight W[O][I] (row-major) into LDS transposed T[I][O].
template<int O, int I>
__device__ __forceinline__ void stage_T(const float* __restrict__ g, float* __restrict__ T) {
    for (int base = threadIdx.x * 4; base < O * I; base += NT * 4) {
        const float4 w = *(const float4*)(g + base);
        const int o = base / I;
        const int i = base % I;
        T[(i + 0) * O + o] = w.x;
        T[(i + 1) * O + o] = w.y;
        T[(i + 2) * O + o] = w.z;
        T[(i + 3) * O + o] = w.w;
    }
}

// out[t][o] = act(bias[o] + sum_i in[t][i] * T[i][o]); ACT: 0=none,1=softplus,2=relu
template<int I, int O, int ACT>
__device__ __forceinline__ void mlp_layer(const float* __restrict__ T,
                                          const float* __restrict__ bias,
                                          const float* __restrict__ in, int inStride,
                                          float* __restrict__ out, int outStride) {
    const int tid = threadIdx.x;
    constexpr int TOT = TRAJ * O;
    for (int e = tid; e < TOT; e += NT) {
        const int t = e / O;
        const int o = e % O;
        const float* inr = in + t * inStride;
        f32x2 a2; a2.x = bias[o]; a2.y = 0.0f;
        #pragma unroll 4
        for (int i = 0; i < I; i += 2) {
            f32x2 xv; xv.x = inr[i];        xv.y = inr[i + 1];
            f32x2 wv; wv.x = T[i * O + o];  wv.y = T[(i + 1) * O + o];
            a2 = FMA2(xv, wv, a2);
        }
        float acc = a2.x + a2.y;
        if (ACT == 1) acc = sp_act(acc);
        else if (ACT == 2) acc = fmaxf(acc, 0.0f);
        out[t * outStride + o] = acc;
    }
}

// Issue one chunk (8 k-pairs) of weights into a NAMED register buffer (literal indices only).
#define LOADC(C, P) do {                                           \
    P##0 = wq[(8 * (C) + 0) * 512]; P##1 = wq[(8 * (C) + 1) * 512]; \
    P##2 = wq[(8 * (C) + 2) * 512]; P##3 = wq[(8 * (C) + 3) * 512]; \
    P##4 = wq[(8 * (C) + 4) * 512]; P##5 = wq[(8 * (C) + 5) * 512]; \
    P##6 = wq[(8 * (C) + 6) * 512]; P##7 = wq[(8 * (C) + 7) * 512]; \
} while (0)

// 4 columns (n = 4*tid+j) x one k-pair, one trajectory: 4 dot2 ops.
#define D4(W, U) do {                              \
    acc[0][t] = dot2bf((W).x, (U), acc[0][t]);     \
    acc[1][t] = dot2bf((W).y, (U), acc[1][t]);     \
    acc[2][t] = dot2bf((W).z, (U), acc[2][t]);     \
    acc[3][t] = dot2bf((W).w, (U), acc[3][t]);     \
} while (0)

// Consume one chunk: 8 k-pairs x 4 cols x TRAJ = 128 dot2. Activation pairs are
// broadcast LDS reads (all lanes same addr -> conflict-free).
#define DOTC(C, P) do {                                                    \
    _Pragma("unroll")                                                      \
    for (int t = 0; t < TRAJ; ++t) {                                       \
        const uint4 u0 = *(const uint4*)(h2b + t * 128 + 16 * (C));        \
        const uint4 u1 = *(const uint4*)(h2b + t * 128 + 16 * (C) + 8);    \
        D4(P##0, u0.x); D4(P##1, u0.y); D4(P##2, u0.z); D4(P##3, u0.w);    \
        D4(P##4, u1.x); D4(P##5, u1.y); D4(P##6, u1.z); D4(P##7, u1.w);    \
    }                                                                      \
} while (0)

__global__ __launch_bounds__(NT, 1)
void cde_kernel(const float* __restrict__ ts,
                const float* __restrict__ coef_d, const float* __restrict__ coef_c,
                const float* __restrict__ coef_b, const float* __restrict__ coef_a,
                const float* __restrict__ iW1, const float* __restrict__ ib1,
                const float* __restrict__ iW2, const float* __restrict__ ib2,
                const float* __restrict__ iW3, const float* __restrict__ ib3,
                const float* __restrict__ fW1, const float* __restrict__ fb1,
                const float* __restrict__ fW2, const float* __restrict__ fb2,
                const float* __restrict__ fb3,
                const float* __restrict__ dW1, const float* __restrict__ db1,
                const float* __restrict__ dW2, const float* __restrict__ db2,
                const float* __restrict__ dW3, const float* __restrict__ db3,
                const unsigned int* __restrict__ fW3P,
                float* __restrict__ outp)
{
    // R0's proven LDS plan: wreg union (init 112KB / main 96KB / decoder 104KB).
    // k2s dropped (fused Heun update), h2b (1KB) added -> total 124928 B, same as R0.
    __shared__ __align__(16) float wreg[28672];
    __shared__ __align__(16) float h1s[TRAJ * 128], h2s[TRAJ * 128];
    __shared__ __align__(16) float ys[TRAJ * 64], ys2[TRAJ * 64], k1s[TRAJ * 64];
    __shared__ __align__(16) float dXs[TRAJ * 32], a0s[TRAJ * 32];
    __shared__ __align__(16) float fb1s[128], fb2s[128];
    __shared__ __align__(16) unsigned short h2b[TRAJ * 128];   // bf16 activations

    const int tid = threadIdx.x;
    const int bbase = blockIdx.x * TRAJ;

    const float ts0 = ts[0];
    const float dt = (ts[Lk - 1] - ts0) / (float)NSTEPS;
    const float hdt = 0.5f * dt;
    const float4 fb3r = *((const float4*)fb3 + tid);       // n = 4*tid .. 4*tid+3 (bias stays f32)
    const uint4* wq = (const uint4*)fW3P + tid;            // row stride 512 uint4 (8 KB)

    // ---- initial condition: y0 = sp(MLP_i(coef_a[:,0,:])) ----
    if (tid < TRAJ * 32) {
        const int t = tid >> 5, d = tid & 31;
        a0s[t * 32 + d] = coef_a[((size_t)(bbase + t) * 199) * 32 + d];
    }
    stage_T<128, 32>(iW1, wreg);                       // iT1 [32][128]
    stage_T<128, 128>(iW2, wreg + 32 * 128);           // iT2 [128][128]
    stage_T<64, 128>(iW3, wreg + 32 * 128 + 128 * 128);// iT3 [128][64]
    if (tid < 128) { fb1s[tid] = fb1[tid]; fb2s[tid] = fb2[tid]; }
    __syncthreads();
    mlp_layer<32, 128, 1>(wreg, ib1, a0s, 32, h1s, 128);
    __syncthreads();
    mlp_layer<128, 128, 1>(wreg + 32 * 128, ib2, h1s, 128, h2s, 128);
    __syncthreads();
    mlp_layer<128, 64, 1>(wreg + 32 * 128 + 128 * 128, ib3, h2s, 128, ys, 64);
    __syncthreads();

    // ---- stage vector-field small weights (resident for all 200 evals) ----
    stage_T<128, 64>(fW1, wreg);                       // wT1 [64][128]
    stage_T<128, 128>(fW2, wreg + 64 * 128);           // wT2 [128][128]
    __syncthreads();

    // ---- Heun, 100 steps = 200 evals; fused state update in owner lanes ----
    #pragma unroll 1
    for (int e = 0; e < 2 * NSTEPS; ++e) {
        const bool k2e = e & 1;
        const float t1 = ts0 + (float)(e >> 1) * dt + (k2e ? dt : 0.0f);
        const float* yin  = k2e ? ys2 : ys;
        float*       yout = k2e ? ys  : ys2;

        // Issue chunks 0-2 (24 of 64 weight loads) FIRST: their L2 time hides
        // under spline + the two small MLP layers.
        uint4 qA0, qA1, qA2, qA3, qA4, qA5, qA6, qA7;
        uint4 qB0, qB1, qB2, qB3, qB4, qB5, qB6, qB7;
        uint4 qC0, qC1, qC2, qC3, qC4, qC5, qC6, qC7;
        LOADC(0, qA); LOADC(1, qB); LOADC(2, qC);

        // cubic-spline derivative dX/dt at scalar time t1
        if (tid < TRAJ * 32) {
            int i = (int)floorf(t1);
            i = min(max(i, 0), Lk - 2);
            const float frac = t1 - ts[i];
            const int tt = tid >> 5, d = tid & 31;
            const size_t off = ((size_t)(bbase + tt) * 199 + (size_t)i) * 32 + d;
            dXs[tid] = coef_b[off] + frac * (2.0f * coef_c[off] + 3.0f * frac * coef_d[off]);
        }

        mlp_layer<64, 128, 1>(wreg, fb1s, yin, 64, h1s, 128);
        __syncthreads();

        // layer2 (f32 math, R0-identical) -> bf16 activations in h2b
        {
            const int t = tid >> 7, o = tid & 127;
            const float* inr = h1s + t * 128;
            f32x2 a2; a2.x = fb2s[o]; a2.y = 0.0f;
            #pragma unroll 4
            for (int i = 0; i < 128; i += 2) {
                f32x2 xv; xv.x = inr[i];                       xv.y = inr[i + 1];
                f32x2 wv; wv.x = wreg[64 * 128 + i * 128 + o]; wv.y = wreg[64 * 128 + (i + 1) * 128 + o];
                a2 = FMA2(xv, wv, a2);
            }
            h2b[t * 128 + o] = (unsigned short)f2bf(sp_act(a2.x + a2.y));
        }
        __syncthreads();

        // Big layer: 8 chunks, compute chunk c while chunk c+3 streams (3-buffer ring,
        // all register indices literal). 1024 dot2 + 64 uint4 loads per thread.
        float acc[4][4];
        #pragma unroll
        for (int j = 0; j < 4; ++j)
            #pragma unroll
            for (int t = 0; t < 4; ++t) acc[j][t] = 0.0f;

        DOTC(0, qA); LOADC(3, qA);
        DOTC(1, qB); LOADC(4, qB);
        DOTC(2, qC); LOADC(5, qC);
        DOTC(3, qA); LOADC(6, qA);
        DOTC(4, qB); LOADC(7, qB);
        DOTC(5, qC);
        DOTC(6, qA);
        DOTC(7, qB);

        // einsum over d (R0-proven mapping): n = 4*tid+j -> h = tid>>3, d = 4*(tid&7)+j
        const int dbase = 4 * (tid & 7);
        float part[TRAJ];
        #pragma unroll
        for (int t = 0; t < TRAJ; ++t) {
            const float4 dx = *(const float4*)(dXs + t * 32 + dbase);
            part[t] = (acc[0][t] + fb3r.x) * dx.x + (acc[1][t] + fb3r.y) * dx.y +
                      (acc[2][t] + fb3r.z) * dx.z + (acc[3][t] + fb3r.w) * dx.w;
        }
        #pragma unroll
        for (int m = 1; m < 8; m <<= 1) {
            #pragma unroll
            for (int t = 0; t < TRAJ; ++t) part[t] += __shfl_xor(part[t], m, 64);
        }

        // owner lanes: write k1 and fused Heun update (saves a pass + a barrier)
        if ((tid & 7) == 0) {
            const int h = tid >> 3;
            #pragma unroll
            for (int t = 0; t < TRAJ; ++t) {
                const int idx = t * 64 + h;
                const float kq = part[t];
                if (!k2e) { k1s[idx] = kq; yout[idx] = ys[idx] + dt * kq; }
                else      {                yout[idx] = ys[idx] + hdt * (k1s[idx] + kq); }
            }
        }
        __syncthreads();
    }

    // ---- decoder: Linear->relu->Linear->relu->Linear ----
    stage_T<128, 64>(dW1, wreg);                          // dT1 [64][128]
    stage_T<128, 128>(dW2, wreg + 64 * 128);              // dT2 [128][128]
    stage_T<16, 128>(dW3, wreg + 64 * 128 + 128 * 128);   // dT3 [128][16]
    __syncthreads();
    mlp_layer<64, 128, 2>(wreg, db1, ys, 64, h1s, 128);
    __syncthreads();
    mlp_layer<128, 128, 2>(wreg + 64 * 128, db2, h1s, 128, h2s, 128);
    __syncthreads();
    mlp_layer<128, 16, 0>(wreg + 64 * 128 + 128 * 128, db3, h2s, 128,
                          outp + (size_t)bbase * 16, 16);
}

extern "C" void kernel_launch(void* const* d_in, const int* in_sizes, int n_in,
                              void* d_out, int out_size, void* d_ws, size_t ws_size,
                              hipStream_t stream) {
    (void)in_sizes; (void)n_in; (void)out_size; (void)ws_size;
    const float* ts     = (const float*)d_in[0];
    const float* coef_d = (const float*)d_in[1];
    const float* coef_c = (const float*)d_in[2];
    const float* coef_b = (const float*)d_in[3];
    const float* coef_a = (const float*)d_in[4];
    const float* iW1 = (const float*)d_in[5];  const float* ib1 = (const float*)d_in[6];
    const float* iW2 = (const float*)d_in[7];  const float* ib2 = (const float*)d_in[8];
    const float* iW3 = (const float*)d_in[9];  const float* ib3 = (const float*)d_in[10];
    const float* fW1 = (const float*)d_in[11]; const float* fb1 = (const float*)d_in[12];
    const float* fW2 = (const float*)d_in[13]; const float* fb2 = (const float*)d_in[14];
    const float* fW3 = (const float*)d_in[15]; const float* fb3 = (const float*)d_in[16];
    const float* dW1 = (const float*)d_in[17]; const float* db1 = (const float*)d_in[18];
    const float* dW2 = (const float*)d_in[19]; const float* db2 = (const float*)d_in[20];
    const float* dW3 = (const float*)d_in[21]; const float* db3 = (const float*)d_in[22];

    unsigned int* fW3P = (unsigned int*)d_ws;   // 512 KB: fW3 bf16 k-pairs, [64 kp][2048 n]

    fw3_packp<<<512, 256, 0, stream>>>(fW3, fW3P);
    cde_kernel<<<256, NT, 0, stream>>>(ts, coef_d, coef_c, coef_b, coef_a,
                                       iW1, ib1, iW2, ib2, iW3, ib3,
                                       fW1, fb1, fW2, fb2, fb3,
                                       dW1, db1, dW2, db2, dW3, db3,
                                       fW3P, (float*)d_out);
}